// Round 1
// baseline (290.872 us; speedup 1.0000x reference)
//
#include <hip/hip_runtime.h>

#define BATCH  2048
#define TLEN   128
#define CH     5
#define NSTEP  (TLEN - 1)      // 127
#define SIGDIM 780             // 5 + 25 + 125 + 625
#define KACC   16              // accumulator copies to spread atomic contention

// One 64-lane wave per path. Lanes 0..4 own S1[lane]; lanes 0..24 own S2[lane]
// (a=lane/5, b=lane%5). Every lane owns level-3 prefixes {2*lane, 2*lane+1}
// (< 125) with S3 in registers and the 5 level-4 elements per prefix (10 regs).
__global__ __launch_bounds__(64) void sig_kernel(
    const float* __restrict__ x, const float* __restrict__ y,
    const float* __restrict__ sigma, float* __restrict__ acc) {
  const int b    = blockIdx.x;
  const bool isX = (b < BATCH);
  const int p    = isX ? b : b - BATCH;
  const float* src = (isX ? x : y) + (size_t)p * (TLEN * CH);
  const int lane = threadIdx.x;

  __shared__ float dxs[NSTEP * 8];   // increments, [t][0..4], stride 8 (16B-aligned float4)
  __shared__ float raw[TLEN * CH];   // 640 floats
  __shared__ float P1[5], Q1[5], R1[5];
  __shared__ float P2[25], Q2[25];

  // coalesced path load
  for (int i = lane; i < TLEN * CH; i += 64) raw[i] = src[i];
  __syncthreads();
  // increments (+ adversarial sigma scaling on x's non-time channels; linear,
  // so scaling increments == scaling the path)
  for (int i = lane; i < NSTEP * CH; i += 64) {
    int t = i / CH, c = i - t * CH;
    float s = (isX && c > 0) ? sigma[c - 1] : 1.0f;
    dxs[t * 8 + c] = (raw[(t + 1) * CH + c] - raw[t * CH + c]) * s;
  }
  __syncthreads();

  // per-lane static indices
  const int a_ = lane / 5, b_ = lane - 5 * (lane / 5);
  const int pfx0 = 2 * lane, pfx1 = 2 * lane + 1;
  const bool v0 = pfx0 < 125, v1 = pfx1 < 125;
  const int ab0 = pfx0 / 5, c0 = pfx0 - 5 * ab0;
  const int ab1 = pfx1 / 5, c1 = pfx1 - 5 * ab1;

  float s1 = 0.f;                       // lanes 0..4
  float s2 = 0.f;                       // lanes 0..24
  float s3a = 0.f, s3b = 0.f;           // owned level-3 prefixes
  float s4[10] = {0.f,0.f,0.f,0.f,0.f,0.f,0.f,0.f,0.f,0.f};

  for (int t = 0; t < NSTEP; ++t) {
    const float* dxt = &dxs[t * 8];
    // ---- phase A: level-1 owners compute prefix helpers from OLD S1
    if (lane < 5) {
      float d = dxt[lane];
      P1[lane] = s1 * (1.f / 6.f) + d * (1.f / 24.f);
      Q1[lane] = s1 * 0.5f        + d * (1.f / 6.f);
      R1[lane] = s1               + d * 0.5f;
      s1 += d;
    }
    __syncthreads();
    // ---- phase B: level-2 owners (OLD S2)
    if (lane < 25) {
      float db = dxt[b_];
      float p2 = 0.5f * s2 + db * P1[a_];
      float q2 =        s2 + db * Q1[a_];
      s2 += db * R1[a_];
      P2[lane] = p2;
      Q2[lane] = q2;
    }
    __syncthreads();
    // ---- phase C: level-3/4 update, all in registers
    float d0 = dxt[0], d1 = dxt[1], d2 = dxt[2], d3 = dxt[3], d4 = dxt[4];
    if (v0) {
      float dc = dxt[c0];
      float p3 = s3a + dc * P2[ab0];
      s3a += dc * Q2[ab0];
      s4[0] += d0 * p3; s4[1] += d1 * p3; s4[2] += d2 * p3;
      s4[3] += d3 * p3; s4[4] += d4 * p3;
    }
    if (v1) {
      float dc = dxt[c1];
      float p3 = s3b + dc * P2[ab1];
      s3b += dc * Q2[ab1];
      s4[5] += d0 * p3; s4[6] += d1 * p3; s4[7] += d2 * p3;
      s4[8] += d3 * p3; s4[9] += d4 * p3;
    }
    __syncthreads();  // WAR guard before next iteration's P*/Q* writes
  }

  // signed accumulate into one of KACC copies: acc holds u - v
  const float w = isX ? 1.0f : -1.0f;
  float* ap = acc + (size_t)(b & (KACC - 1)) * SIGDIM;
  if (lane < 5)  atomicAdd(ap + lane, w * s1);
  if (lane < 25) atomicAdd(ap + 5 + lane, w * s2);
  if (v0) {
    atomicAdd(ap + 30 + pfx0, w * s3a);
    #pragma unroll
    for (int d = 0; d < 5; ++d) atomicAdd(ap + 155 + pfx0 * 5 + d, w * s4[d]);
  }
  if (v1) {
    atomicAdd(ap + 30 + pfx1, w * s3b);
    #pragma unroll
    for (int d = 0; d < 5; ++d) atomicAdd(ap + 155 + pfx1 * 5 + d, w * s4[5 + d]);
  }
}

__global__ __launch_bounds__(256) void reduce_kernel(
    const float* __restrict__ acc, float* __restrict__ out) {
  const int tid = threadIdx.x;
  float local = 0.f;
  for (int p2 = tid; p2 < SIGDIM; p2 += 256) {
    float v = 0.f;
    #pragma unroll
    for (int k = 0; k < KACC; ++k) v += acc[(size_t)k * SIGDIM + p2];
    local += v * v;
  }
  #pragma unroll
  for (int off = 32; off > 0; off >>= 1) local += __shfl_down(local, off, 64);
  __shared__ float red[4];
  if ((tid & 63) == 0) red[tid >> 6] = local;
  __syncthreads();
  if (tid == 0) {
    float tot = red[0] + red[1] + red[2] + red[3];
    out[0] = tot / (2048.0f * 2048.0f);
  }
}

extern "C" void kernel_launch(void* const* d_in, const int* in_sizes, int n_in,
                              void* d_out, int out_size, void* d_ws, size_t ws_size,
                              hipStream_t stream) {
  const float* x     = (const float*)d_in[0];
  const float* y     = (const float*)d_in[1];
  const float* sigma = (const float*)d_in[2];
  float* out = (float*)d_out;
  float* acc = (float*)d_ws;

  hipMemsetAsync(acc, 0, (size_t)KACC * SIGDIM * sizeof(float), stream);
  sig_kernel<<<dim3(2 * BATCH), dim3(64), 0, stream>>>(x, y, sigma, acc);
  reduce_kernel<<<dim3(1), dim3(256), 0, stream>>>(acc, out);
}

// Round 2
// 127.009 us; speedup vs baseline: 2.2902x; 2.2902x over previous
//
#include <hip/hip_runtime.h>

#define BATCH  2048
#define TLEN   128
#define CH     5
#define NSTEP  (TLEN - 1)      // 127
#define SIGDIM 780             // 5 + 25 + 125 + 625
#define KACC   16              // global accumulator copies (spread atomic contention)
#define WPB    4               // waves (= paths) per block

// One 64-lane wave per path; 4 paths per 256-thread block.
// Lane l (<50): owns level-2 chain ab = l>>1 (a=ab/5, b=ab%5), tracked redundantly
// (both lanes of the pair track the same chain; even lane publishes it).
// Even lane owns level-3 prefixes (ab, c) for c in {0,1,2}; odd lane c in {3,4}.
// Each owned prefix carries its 5 level-4 accumulators in registers.
// Main loop: NO barriers, NO shuffles, only 2 broadcast LDS reads per step.
__global__ __launch_bounds__(256) void sig_kernel(
    const float* __restrict__ x, const float* __restrict__ y,
    const float* __restrict__ sigma, float* __restrict__ acc) {
  const int wave = threadIdx.x >> 6;
  const int lane = threadIdx.x & 63;
  const int b    = blockIdx.x * WPB + wave;          // 0..4095 (block-uniform sign: BATCH%WPB==0)
  const bool isX = (b < BATCH);
  const int  p   = isX ? b : b - BATCH;
  const float* src = (isX ? x : y) + (size_t)p * (TLEN * CH);

  __shared__ __align__(16) float dxs[WPB][NSTEP * 8]; // per-wave increments, stride 8 (32B rows)
  __shared__ float blockAcc[SIGDIM];

  for (int i = threadIdx.x; i < SIGDIM; i += 256) blockAcc[i] = 0.f;

  // increments (sigma folds linearly into x's non-time channels)
  float* dxw = dxs[wave];
  for (int i = lane; i < NSTEP * CH; i += 64) {
    int t = i / CH, c = i - CH * t;
    float v = src[i + CH] - src[i];
    if (isX && c > 0) v *= sigma[c - 1];
    dxw[t * 8 + c] = v;
  }
  __syncthreads();   // one-time: fill visible to own wave, blockAcc zeroed

  const int  ab   = (lane >> 1) < 25 ? (lane >> 1) : 24;   // clamp for idle lanes 50..63
  const int  a_   = ab / 5, b_ = ab - 5 * a_;
  const bool odd  = (lane & 1);
  const bool act  = (lane < 50);

  float s1a = 0.f, s2 = 0.f;
  float s30 = 0.f, s31 = 0.f, s32 = 0.f;
  float s40[5] = {0,0,0,0,0}, s41[5] = {0,0,0,0,0}, s42[5] = {0,0,0,0,0};

  #pragma unroll 2
  for (int t = 0; t < NSTEP; ++t) {
    const float4 dv = *(const float4*)(dxw + t * 8);
    const float d4  = dxw[t * 8 + 4];
    const float d0 = dv.x, d1 = dv.y, d2 = dv.z, d3 = dv.w;
    const float da  = a_ == 0 ? d0 : a_ == 1 ? d1 : a_ == 2 ? d2 : a_ == 3 ? d3 : d4;
    const float db  = b_ == 0 ? d0 : b_ == 1 ? d1 : b_ == 2 ? d2 : b_ == 3 ? d3 : d4;
    const float dc0 = odd ? d3 : d0;
    const float dc1 = odd ? d4 : d1;
    const float dc2 = d2;
    // level-1 chain (old s1a)
    const float pa = s1a * (1.f / 6.f) + da * (1.f / 24.f);
    const float qa = s1a * 0.5f        + da * (1.f / 6.f);
    const float ra = s1a               + da * 0.5f;
    s1a += da;
    // level-2 chain (old s2)
    const float p2 = 0.5f * s2 + db * pa;
    const float q2 =        s2 + db * qa;
    s2 += db * ra;
    // level-3/4 (old s3)
    const float p30 = s30 + dc0 * p2;  s30 += dc0 * q2;
    const float p31 = s31 + dc1 * p2;  s31 += dc1 * q2;
    const float p32 = s32 + dc2 * p2;  s32 += dc2 * q2;
    s40[0] += d0 * p30; s40[1] += d1 * p30; s40[2] += d2 * p30; s40[3] += d3 * p30; s40[4] += d4 * p30;
    s41[0] += d0 * p31; s41[1] += d1 * p31; s41[2] += d2 * p31; s41[3] += d3 * p31; s41[4] += d4 * p31;
    s42[0] += d0 * p32; s42[1] += d1 * p32; s42[2] += d2 * p32; s42[3] += d3 * p32; s42[4] += d4 * p32;
  }

  // block-local accumulation in LDS (lanes hit distinct addrs; cross-wave via LDS atomics)
  if (act) {
    const int c0 = odd ? 3 : 0, c1 = odd ? 4 : 1;
    const int base3 = 30 + ab * 5;
    if ((lane % 10) == 0) atomicAdd(&blockAcc[lane / 10], s1a);   // b_==0 even lanes: a = lane/10
    if (!odd)             atomicAdd(&blockAcc[5 + ab], s2);
    atomicAdd(&blockAcc[base3 + c0], s30);
    atomicAdd(&blockAcc[base3 + c1], s31);
    if (!odd) atomicAdd(&blockAcc[base3 + 2], s32);
    const int b40 = 155 + (ab * 5 + c0) * 5;
    const int b41 = 155 + (ab * 5 + c1) * 5;
    const int b42 = 155 + (ab * 5 + 2) * 5;
    #pragma unroll
    for (int d = 0; d < 5; ++d) atomicAdd(&blockAcc[b40 + d], s40[d]);
    #pragma unroll
    for (int d = 0; d < 5; ++d) atomicAdd(&blockAcc[b41 + d], s41[d]);
    if (!odd) {
      #pragma unroll
      for (int d = 0; d < 5; ++d) atomicAdd(&blockAcc[b42 + d], s42[d]);
    }
  }
  __syncthreads();

  // block -> global, signed (sign is block-uniform)
  const float w = (blockIdx.x < (BATCH / WPB)) ? 1.0f : -1.0f;
  float* ap = acc + (size_t)(blockIdx.x & (KACC - 1)) * SIGDIM;
  for (int i = threadIdx.x; i < SIGDIM; i += 256)
    atomicAdd(ap + i, w * blockAcc[i]);
}

__global__ __launch_bounds__(256) void reduce_kernel(
    const float* __restrict__ acc, float* __restrict__ out) {
  const int tid = threadIdx.x;
  float local = 0.f;
  for (int i = tid; i < SIGDIM; i += 256) {
    float v = 0.f;
    #pragma unroll
    for (int k = 0; k < KACC; ++k) v += acc[(size_t)k * SIGDIM + i];
    local += v * v;
  }
  #pragma unroll
  for (int off = 32; off > 0; off >>= 1) local += __shfl_down(local, off, 64);
  __shared__ float red[4];
  if ((tid & 63) == 0) red[tid >> 6] = local;
  __syncthreads();
  if (tid == 0) {
    out[0] = (red[0] + red[1] + red[2] + red[3]) / (2048.0f * 2048.0f);
  }
}

extern "C" void kernel_launch(void* const* d_in, const int* in_sizes, int n_in,
                              void* d_out, int out_size, void* d_ws, size_t ws_size,
                              hipStream_t stream) {
  const float* x     = (const float*)d_in[0];
  const float* y     = (const float*)d_in[1];
  const float* sigma = (const float*)d_in[2];
  float* out = (float*)d_out;
  float* acc = (float*)d_ws;

  hipMemsetAsync(acc, 0, (size_t)KACC * SIGDIM * sizeof(float), stream);
  sig_kernel<<<dim3((2 * BATCH) / WPB), dim3(256), 0, stream>>>(x, y, sigma, acc);
  reduce_kernel<<<dim3(1), dim3(256), 0, stream>>>(acc, out);
}

// Round 3
// 118.761 us; speedup vs baseline: 2.4492x; 1.0695x over previous
//
#include <hip/hip_runtime.h>

#define BATCH  2048
#define TLEN   128
#define CH     5
#define NSTEP  (TLEN - 1)      // 127
#define SIGDIM 780             // 5 + 25 + 125 + 625
#define KACC   16              // global accumulator copies (spread atomic contention)
#define WPB    4               // waves (= paths) per block
#define NBLK   ((2 * BATCH) / WPB)   // 1024

// One 64-lane wave per path; 4 paths per 256-thread block.
// Lane l (<50): pair-owns level-2 chain ab = l>>1 (a=ab/5, b=ab%5), tracked
// redundantly; even lane publishes it. Even lane owns level-3 prefixes (ab,c)
// c in {0,1,2}; odd lane c in {3,4} (s32/s42 computed by both, published by even).
// Main loop: no barriers/shuffles; all channel selects are broadcast LDS reads,
// software-pipelined 1 deep. Final reduction fused via last-block-done counter.
__global__ __launch_bounds__(256) void sig_kernel(
    const float* __restrict__ x, const float* __restrict__ y,
    const float* __restrict__ sigma, float* __restrict__ acc,
    unsigned int* __restrict__ counter, float* __restrict__ out) {
  const int wave = threadIdx.x >> 6;
  const int lane = threadIdx.x & 63;
  const int b    = blockIdx.x * WPB + wave;          // 0..4095 (sign block-uniform)
  const bool isX = (b < BATCH);
  const int  p   = isX ? b : b - BATCH;
  const float* src = (isX ? x : y) + (size_t)p * (TLEN * CH);

  __shared__ __align__(16) float dxs[WPB][TLEN * 8]; // row t: [d0..d4,pad×3]; row 127 = dummy prefetch target
  __shared__ float blockAcc[SIGDIM];
  __shared__ float red[4];
  __shared__ unsigned int lastFlag;

  for (int i = threadIdx.x; i < SIGDIM; i += 256) blockAcc[i] = 0.f;

  float* dxw = dxs[wave];
  for (int i = lane; i < NSTEP * CH; i += 64) {
    int t = i / CH, c = i - CH * t;
    float v = src[i + CH] - src[i];
    if (isX && c > 0) v *= sigma[c - 1];
    dxw[t * 8 + c] = v;
  }
  if (lane < 8) dxw[NSTEP * 8 + lane] = 0.f;   // dummy row for prefetch overrun
  __syncthreads();   // fill visible, blockAcc zeroed

  const int  ab  = (lane >> 1) < 25 ? (lane >> 1) : 24;  // clamp idle lanes 50..63
  const int  a_  = ab / 5, b_ = ab - 5 * a_;
  const bool odd = (lane & 1);
  const int  c0i = odd ? 3 : 0, c1i = odd ? 4 : 1;
  const bool act = (lane < 50);

  float s1a = 0.f, s2 = 0.f;
  float s30 = 0.f, s31 = 0.f, s32 = 0.f;
  float s40[5] = {0,0,0,0,0}, s41[5] = {0,0,0,0,0}, s42[5] = {0,0,0,0,0};

  // software-pipeline prologue: load step 0
  float4 dvn = *(const float4*)dxw;
  float  d4n = dxw[4], dan = dxw[a_], dbn = dxw[b_];
  float  dc0n = dxw[c0i], dc1n = dxw[c1i];

  #pragma unroll 4
  for (int t = 0; t < NSTEP; ++t) {
    const float d0 = dvn.x, d1 = dvn.y, d2 = dvn.z, d3 = dvn.w, d4 = d4n;
    const float da = dan, db = dbn, dc0 = dc0n, dc1 = dc1n, dc2 = d2;
    // prefetch step t+1 (row 127 is a zeroed dummy on the last iteration)
    const float* nx = dxw + (t + 1) * 8;
    dvn = *(const float4*)nx;
    d4n = nx[4]; dan = nx[a_]; dbn = nx[b_]; dc0n = nx[c0i]; dc1n = nx[c1i];

    // level-1 chain (old s1a)
    const float pa = s1a * (1.f / 6.f) + da * (1.f / 24.f);
    const float qa = s1a * 0.5f        + da * (1.f / 6.f);
    const float ra = s1a               + da * 0.5f;
    s1a += da;
    // level-2 chain (old s2)
    const float p2 = 0.5f * s2 + db * pa;
    const float q2 =        s2 + db * qa;
    s2 += db * ra;
    // level-3/4 (old s3)
    const float p30 = s30 + dc0 * p2;  s30 += dc0 * q2;
    const float p31 = s31 + dc1 * p2;  s31 += dc1 * q2;
    const float p32 = s32 + dc2 * p2;  s32 += dc2 * q2;
    s40[0] += d0 * p30; s40[1] += d1 * p30; s40[2] += d2 * p30; s40[3] += d3 * p30; s40[4] += d4 * p30;
    s41[0] += d0 * p31; s41[1] += d1 * p31; s41[2] += d2 * p31; s41[3] += d3 * p31; s41[4] += d4 * p31;
    s42[0] += d0 * p32; s42[1] += d1 * p32; s42[2] += d2 * p32; s42[3] += d3 * p32; s42[4] += d4 * p32;
  }

  // block-local accumulation in LDS
  if (act) {
    const int base3 = 30 + ab * 5;
    if ((lane % 10) == 0) atomicAdd(&blockAcc[lane / 10], s1a);
    if (!odd)             atomicAdd(&blockAcc[5 + ab], s2);
    atomicAdd(&blockAcc[base3 + c0i], s30);
    atomicAdd(&blockAcc[base3 + c1i], s31);
    if (!odd) atomicAdd(&blockAcc[base3 + 2], s32);
    const int b40 = 155 + (ab * 5 + c0i) * 5;
    const int b41 = 155 + (ab * 5 + c1i) * 5;
    const int b42 = 155 + (ab * 5 + 2) * 5;
    #pragma unroll
    for (int d = 0; d < 5; ++d) atomicAdd(&blockAcc[b40 + d], s40[d]);
    #pragma unroll
    for (int d = 0; d < 5; ++d) atomicAdd(&blockAcc[b41 + d], s41[d]);
    if (!odd) {
      #pragma unroll
      for (int d = 0; d < 5; ++d) atomicAdd(&blockAcc[b42 + d], s42[d]);
    }
  }
  __syncthreads();

  // block -> global, signed (sign is block-uniform)
  const float w = (blockIdx.x < (BATCH / WPB)) ? 1.0f : -1.0f;
  float* ap = acc + (size_t)(blockIdx.x & (KACC - 1)) * SIGDIM;
  for (int i = threadIdx.x; i < SIGDIM; i += 256)
    atomicAdd(ap + i, w * blockAcc[i]);

  // ---- fused final reduction: last block to finish does it ----
  __syncthreads();                 // all global atomics issued by this block
  if (threadIdx.x == 0) {
    __threadfence();               // release our atomics to agent scope
    unsigned int old = __hip_atomic_fetch_add(counter, 1u, __ATOMIC_ACQ_REL,
                                              __HIP_MEMORY_SCOPE_AGENT);
    lastFlag = (old == NBLK - 1) ? 1u : 0u;
  }
  __syncthreads();
  if (lastFlag) {
    const int tid = threadIdx.x;
    float local = 0.f;
    for (int i = tid; i < SIGDIM; i += 256) {
      float v = 0.f;
      #pragma unroll
      for (int k = 0; k < KACC; ++k)
        v += __hip_atomic_load(&acc[(size_t)k * SIGDIM + i],
                               __ATOMIC_RELAXED, __HIP_MEMORY_SCOPE_AGENT);
      local += v * v;
    }
    #pragma unroll
    for (int off = 32; off > 0; off >>= 1) local += __shfl_down(local, off, 64);
    if ((tid & 63) == 0) red[tid >> 6] = local;
    __syncthreads();
    if (tid == 0)
      out[0] = (red[0] + red[1] + red[2] + red[3]) / (2048.0f * 2048.0f);
  }
}

extern "C" void kernel_launch(void* const* d_in, const int* in_sizes, int n_in,
                              void* d_out, int out_size, void* d_ws, size_t ws_size,
                              hipStream_t stream) {
  const float* x     = (const float*)d_in[0];
  const float* y     = (const float*)d_in[1];
  const float* sigma = (const float*)d_in[2];
  float* out = (float*)d_out;
  float* acc = (float*)d_ws;
  unsigned int* counter = (unsigned int*)((char*)d_ws + (size_t)KACC * SIGDIM * sizeof(float));

  hipMemsetAsync(d_ws, 0, (size_t)KACC * SIGDIM * sizeof(float) + 64, stream);
  sig_kernel<<<dim3(NBLK), dim3(256), 0, stream>>>(x, y, sigma, acc, counter, out);
}